// Round 1
// baseline (9584.227 us; speedup 1.0000x reference)
//
#include <hip/hip_runtime.h>
#include <math.h>

#define H_ENC 128
#define H_DEC 256
#define L_SRC 512
#define T_DEC 96
#define B_TOT 1024

__device__ __forceinline__ float sigmoidf_(float x) {
    x = fminf(fmaxf(x, -30.f), 30.f);
    return 1.f / (1.f + __expf(-x));
}
__device__ __forceinline__ float tanhf_(float x) {
    x = fminf(fmaxf(x, -15.f), 15.f);
    float e = __expf(2.f * x);
    return (e - 1.f) / (e + 1.f);
}

// ---------------- Encoder ----------------
// grid = (B_TOT/G)*2 blocks, 512 threads. Thread t owns gate-row t (Whh row in
// 128 VGPRs). h lives in LDS (broadcast reads). c in regs of threads<128.
#define ENC_G 2
__global__ __launch_bounds__(512, 2) void encoder_kernel(
    const float* __restrict__ source,
    const float* __restrict__ Wih_f, const float* __restrict__ Whh_f, const float* __restrict__ b_f,
    const float* __restrict__ Wih_b, const float* __restrict__ Whh_b, const float* __restrict__ b_b,
    float* __restrict__ h0, float* __restrict__ c0)   // each [B, 2*H_ENC]
{
    const int dir = blockIdx.x & 1;
    const int bg  = blockIdx.x >> 1;
    const int t   = threadIdx.x;          // gate row 0..511

    const float* Wih = dir ? Wih_b : Wih_f;
    const float* Whh = dir ? Whh_b : Whh_f;
    const float* bb  = dir ? b_b   : b_f;

    __shared__ float xs[ENC_G][L_SRC];
    __shared__ float h_lds[ENC_G][H_ENC];
    __shared__ float g_lds[ENC_G][4 * H_ENC];

    // weight row t -> registers (one-time, L2/L3 broadcast across blocks)
    float w[H_ENC];
    #pragma unroll
    for (int k = 0; k < H_ENC; k += 4) {
        float4 v = *reinterpret_cast<const float4*>(Whh + (size_t)t * H_ENC + k);
        w[k] = v.x; w[k + 1] = v.y; w[k + 2] = v.z; w[k + 3] = v.w;
    }
    const float wih  = Wih[t];
    const float bias = bb[t];

    #pragma unroll
    for (int g = 0; g < ENC_G; ++g) {
        int b = bg * ENC_G + g;
        xs[g][t] = source[(size_t)b * L_SRC + t];     // 512 threads, 512 steps
        if (t < H_ENC) h_lds[g][t] = 0.f;
    }
    float c[ENC_G];
    #pragma unroll
    for (int g = 0; g < ENC_G; ++g) c[g] = 0.f;
    __syncthreads();

    for (int s = 0; s < L_SRC; ++s) {
        const int step = dir ? (L_SRC - 1 - s) : s;
        float acc[ENC_G];
        #pragma unroll
        for (int g = 0; g < ENC_G; ++g) acc[g] = bias + wih * xs[g][step];

        #pragma unroll
        for (int k = 0; k < H_ENC; k += 4) {
            #pragma unroll
            for (int g = 0; g < ENC_G; ++g) {
                float4 hv = *reinterpret_cast<const float4*>(&h_lds[g][k]);
                acc[g] += w[k] * hv.x + w[k + 1] * hv.y + w[k + 2] * hv.z + w[k + 3] * hv.w;
            }
        }
        #pragma unroll
        for (int g = 0; g < ENC_G; ++g) g_lds[g][t] = acc[g];
        __syncthreads();   // gates written; h reads of this step done

        if (t < H_ENC) {
            #pragma unroll
            for (int g = 0; g < ENC_G; ++g) {
                float ig = sigmoidf_(g_lds[g][t]);
                float fg = sigmoidf_(g_lds[g][H_ENC + t]);
                float gg = tanhf_(g_lds[g][2 * H_ENC + t]);
                float og = sigmoidf_(g_lds[g][3 * H_ENC + t]);
                float cn = fg * c[g] + ig * gg;
                c[g] = cn;
                h_lds[g][t] = og * tanhf_(cn);
            }
        }
        __syncthreads();   // new h visible
    }

    if (t < H_ENC) {
        #pragma unroll
        for (int g = 0; g < ENC_G; ++g) {
            int b = bg * ENC_G + g;
            h0[(size_t)b * (2 * H_ENC) + dir * H_ENC + t] = h_lds[g][t];
            c0[(size_t)b * (2 * H_ENC) + dir * H_ENC + t] = c[g];
        }
    }
}

// ---------------- Decoder ----------------
// grid = B/G blocks, 256 threads. Thread t owns h-element t: gate rows
// t (i), 256+t (f), 512+t (g), 768+t (o) streamed from L2 each step.
#define DEC_G 4
__global__ __launch_bounds__(256) void decoder_kernel(
    const float* __restrict__ Wih,   // [1024,1]
    const float* __restrict__ Whh,   // [1024,256]
    const float* __restrict__ bb,    // [1024]
    const float* __restrict__ outW,  // [1,256]
    const float* __restrict__ outb,  // [1]
    const float* __restrict__ h0,    // [B,256]
    const float* __restrict__ c0,    // [B,256]
    float* __restrict__ out)         // [B,T,1]
{
    const int bg = blockIdx.x;
    const int t  = threadIdx.x;
    const int wave = t >> 6, lane = t & 63;

    __shared__ float h_lds[DEC_G][H_DEC];
    __shared__ float y_lds[DEC_G];
    __shared__ float red[4][DEC_G];

    float c[DEC_G];
    #pragma unroll
    for (int g = 0; g < DEC_G; ++g) {
        int b = bg * DEC_G + g;
        h_lds[g][t] = h0[(size_t)b * H_DEC + t];
        c[g] = c0[(size_t)b * H_DEC + t];
    }
    if (t < DEC_G) y_lds[t] = 0.f;

    const float wih_i = Wih[t];
    const float wih_f = Wih[H_DEC + t];
    const float wih_g = Wih[2 * H_DEC + t];
    const float wih_o = Wih[3 * H_DEC + t];
    const float b_i = bb[t], b_f = bb[H_DEC + t], b_g = bb[2 * H_DEC + t], b_o = bb[3 * H_DEC + t];
    const float ow = outW[t];
    const float ob = outb[0];

    const float* Wi = Whh + (size_t)t * H_DEC;
    const float* Wf = Whh + (size_t)(H_DEC + t) * H_DEC;
    const float* Wg = Whh + (size_t)(2 * H_DEC + t) * H_DEC;
    const float* Wo = Whh + (size_t)(3 * H_DEC + t) * H_DEC;

    __syncthreads();

    for (int s = 0; s < T_DEC; ++s) {
        float acc_i[DEC_G], acc_f[DEC_G], acc_g[DEC_G], acc_o[DEC_G];
        #pragma unroll
        for (int g = 0; g < DEC_G; ++g) {
            float yv = y_lds[g];
            acc_i[g] = b_i + wih_i * yv;
            acc_f[g] = b_f + wih_f * yv;
            acc_g[g] = b_g + wih_g * yv;
            acc_o[g] = b_o + wih_o * yv;
        }

        #pragma unroll 2
        for (int k = 0; k < H_DEC; k += 4) {
            float4 wi = *reinterpret_cast<const float4*>(Wi + k);
            float4 wf = *reinterpret_cast<const float4*>(Wf + k);
            float4 wg = *reinterpret_cast<const float4*>(Wg + k);
            float4 wo = *reinterpret_cast<const float4*>(Wo + k);
            #pragma unroll
            for (int g = 0; g < DEC_G; ++g) {
                float4 hv = *reinterpret_cast<const float4*>(&h_lds[g][k]);
                acc_i[g] += wi.x * hv.x + wi.y * hv.y + wi.z * hv.z + wi.w * hv.w;
                acc_f[g] += wf.x * hv.x + wf.y * hv.y + wf.z * hv.z + wf.w * hv.w;
                acc_g[g] += wg.x * hv.x + wg.y * hv.y + wg.z * hv.z + wg.w * hv.w;
                acc_o[g] += wo.x * hv.x + wo.y * hv.y + wo.z * hv.z + wo.w * hv.w;
            }
        }

        float hn[DEC_G];
        #pragma unroll
        for (int g = 0; g < DEC_G; ++g) {
            float ig = sigmoidf_(acc_i[g]);
            float fg = sigmoidf_(acc_f[g]);
            float gg = tanhf_(acc_g[g]);
            float og = sigmoidf_(acc_o[g]);
            c[g] = fg * c[g] + ig * gg;
            hn[g] = og * tanhf_(c[g]);
        }
        __syncthreads();   // h_lds reads of this step complete

        #pragma unroll
        for (int g = 0; g < DEC_G; ++g) {
            h_lds[g][t] = hn[g];
            float p = hn[g] * ow;
            #pragma unroll
            for (int off = 32; off; off >>= 1) p += __shfl_down(p, off);
            if (lane == 0) red[wave][g] = p;
        }
        __syncthreads();   // partials + new h visible

        if (t < DEC_G) {
            float yv = red[0][t] + red[1][t] + red[2][t] + red[3][t] + ob;
            y_lds[t] = yv;
            int b = bg * DEC_G + t;
            out[(size_t)b * T_DEC + s] = yv;
        }
        __syncthreads();   // y visible for next step
    }
}

extern "C" void kernel_launch(void* const* d_in, const int* in_sizes, int n_in,
                              void* d_out, int out_size, void* d_ws, size_t ws_size,
                              hipStream_t stream) {
    const float* source = (const float*)d_in[0];
    // d_in[1] target_tensor: only defines T, unused
    const float* eWih_f = (const float*)d_in[2];
    const float* eWhh_f = (const float*)d_in[3];
    const float* eb_f   = (const float*)d_in[4];
    const float* eWih_b = (const float*)d_in[5];
    const float* eWhh_b = (const float*)d_in[6];
    const float* eb_b   = (const float*)d_in[7];
    const float* dWih   = (const float*)d_in[8];
    const float* dWhh   = (const float*)d_in[9];
    const float* db     = (const float*)d_in[10];
    const float* oW     = (const float*)d_in[11];
    const float* obp    = (const float*)d_in[12];
    float* out = (float*)d_out;

    float* h0 = (float*)d_ws;                  // [1024, 256]
    float* c0 = h0 + (size_t)B_TOT * H_DEC;    // [1024, 256]

    encoder_kernel<<<(B_TOT / ENC_G) * 2, 512, 0, stream>>>(
        source, eWih_f, eWhh_f, eb_f, eWih_b, eWhh_b, eb_b, h0, c0);
    decoder_kernel<<<B_TOT / DEC_G, 256, 0, stream>>>(
        dWih, dWhh, db, oW, obp, h0, c0, out);
}

// Round 2
// 2614.198 us; speedup vs baseline: 3.6662x; 3.6662x over previous
//
#include <hip/hip_runtime.h>
#include <math.h>

#define H_ENC 128
#define H_DEC 256
#define L_SRC 512
#define T_DEC 96
#define B_TOT 1024

typedef _Float16 h2f __attribute__((ext_vector_type(2)));

#if defined(__has_builtin)
#if __has_builtin(__builtin_amdgcn_fdot2)
#define FDOT2(a, b, c) __builtin_amdgcn_fdot2((a), (b), (c), false)
#endif
#endif
#ifndef FDOT2
#define FDOT2(a, b, c) ((c) + (float)(a).x * (float)(b).x + (float)(a).y * (float)(b).y)
#endif

__device__ __forceinline__ h2f as_h2(unsigned u) { union { unsigned u; h2f h; } x; x.u = u; return x.h; }
__device__ __forceinline__ unsigned as_u32(h2f h) { union { h2f h; unsigned u; } x; x.h = h; return x.u; }
__device__ __forceinline__ h2f pack2(float a, float b) { h2f p; p.x = (_Float16)a; p.y = (_Float16)b; return p; }

__device__ __forceinline__ float sigmoidf_(float x) {
    x = fminf(fmaxf(x, -30.f), 30.f);
    return 1.f / (1.f + __expf(-x));
}
__device__ __forceinline__ float tanhf_(float x) {
    x = fminf(fmaxf(x, -15.f), 15.f);
    float e = __expf(2.f * x);
    return (e - 1.f) / (e + 1.f);
}

// ---------------- Encoder ----------------
// 256 threads, ENC_G=4 batches, grid = (1024/4)*2 = 512 blocks (2/CU).
// Thread t owns gate rows rowA=t (i|f) and rowB=256+t (g|o), f16-packed in
// 128 VGPRs. h kept f16-packed in LDS, broadcast-read as uint4.
#define EG 4
__global__ __launch_bounds__(256, 2) void encoder_kernel(
    const float* __restrict__ source,
    const float* __restrict__ Wih_f, const float* __restrict__ Whh_f, const float* __restrict__ b_f,
    const float* __restrict__ Wih_b, const float* __restrict__ Whh_b, const float* __restrict__ b_b,
    float* __restrict__ h0, float* __restrict__ c0)
{
    const int dir = blockIdx.x & 1;
    const int bg  = blockIdx.x >> 1;
    const int t   = threadIdx.x;
    const int lo  = t & 127;
    const int hf  = t >> 7;          // 0: rows (i,g)   1: rows (f,o)

    const float* Wih = dir ? Wih_b : Wih_f;
    const float* Whh = dir ? Whh_b : Whh_f;
    const float* bb  = dir ? b_b   : b_f;

    const int rowA = t;          // i (hf=0) / f (hf=1)
    const int rowB = 256 + t;    // g (hf=0) / o (hf=1)

    __shared__ float  xs[EG][L_SRC];
    __shared__ ushort hU[EG][H_ENC];          // f16 h, pair-packed reads
    __shared__ float  exch[EG][2][H_ENC];     // f,o raw gates from hf=1 half

    // --- one-time: weights to f16 pairs in VGPRs ---
    h2f wA[64], wB[64];
    #pragma unroll
    for (int j = 0; j < 64; ++j) {
        float2 a = *reinterpret_cast<const float2*>(Whh + (size_t)rowA * H_ENC + 2 * j);
        float2 b = *reinterpret_cast<const float2*>(Whh + (size_t)rowB * H_ENC + 2 * j);
        wA[j] = pack2(a.x, a.y);
        wB[j] = pack2(b.x, b.y);
    }
    const float wihA = Wih[rowA], wihB = Wih[rowB];
    const float biasA = bb[rowA], biasB = bb[rowB];

    #pragma unroll
    for (int g = 0; g < EG; ++g) {
        int b = bg * EG + g;
        for (int i = t; i < L_SRC; i += 256) xs[g][i] = source[(size_t)b * L_SRC + i];
        if (t < H_ENC) hU[g][t] = 0;   // f16 zero
    }
    float c[EG], h_last[EG];
    #pragma unroll
    for (int g = 0; g < EG; ++g) { c[g] = 0.f; h_last[g] = 0.f; }
    __syncthreads();

    for (int s = 0; s < L_SRC; ++s) {
        const int step = dir ? (L_SRC - 1 - s) : s;
        float accA[EG], accB[EG];
        #pragma unroll
        for (int g = 0; g < EG; ++g) {
            float x = xs[g][step];
            accA[g] = biasA + wihA * x;
            accB[g] = biasB + wihB * x;
        }

        #pragma unroll
        for (int m = 0; m < 16; ++m) {
            #pragma unroll
            for (int g = 0; g < EG; ++g) {
                uint4 hv = *reinterpret_cast<const uint4*>(&hU[g][8 * m]);
                accA[g] = FDOT2(wA[4 * m + 0], as_h2(hv.x), accA[g]);
                accB[g] = FDOT2(wB[4 * m + 0], as_h2(hv.x), accB[g]);
                accA[g] = FDOT2(wA[4 * m + 1], as_h2(hv.y), accA[g]);
                accB[g] = FDOT2(wB[4 * m + 1], as_h2(hv.y), accB[g]);
                accA[g] = FDOT2(wA[4 * m + 2], as_h2(hv.z), accA[g]);
                accB[g] = FDOT2(wB[4 * m + 2], as_h2(hv.z), accB[g]);
                accA[g] = FDOT2(wA[4 * m + 3], as_h2(hv.w), accA[g]);
                accB[g] = FDOT2(wB[4 * m + 3], as_h2(hv.w), accB[g]);
            }
        }

        if (hf) {
            #pragma unroll
            for (int g = 0; g < EG; ++g) {
                exch[g][0][lo] = accA[g];   // f raw
                exch[g][1][lo] = accB[g];   // o raw
            }
        }
        __syncthreads();   // dots done (hU free), exch visible

        if (!hf) {
            #pragma unroll
            for (int g = 0; g < EG; ++g) {
                float fi = sigmoidf_(exch[g][0][lo]);
                float oo = sigmoidf_(exch[g][1][lo]);
                float ii = sigmoidf_(accA[g]);
                float gg = tanhf_(accB[g]);
                c[g] = fi * c[g] + ii * gg;
                float h = oo * tanhf_(c[g]);
                h_last[g] = h;
                *reinterpret_cast<_Float16*>(&hU[g][lo]) = (_Float16)h;
            }
        }
        __syncthreads();   // new h visible
    }

    if (!hf) {
        #pragma unroll
        for (int g = 0; g < EG; ++g) {
            int b = bg * EG + g;
            h0[(size_t)b * (2 * H_ENC) + dir * H_ENC + lo] = h_last[g];
            c0[(size_t)b * (2 * H_ENC) + dir * H_ENC + lo] = c[g];
        }
    }
}

// ---------------- Decoder ----------------
// 512 threads, DEC_G=4 batches, grid = 256 blocks (1/CU).
// Thread t owns rows rowA=hf*256+lo (i|f), rowB=512+hf*256+lo (g|o).
// k-pairs 0..95 (k<192) live in 192 VGPRs; pairs 96..127 in 135KB LDS
// (pad-33 layout, conflict-free). Zero steady-state global traffic.
#define DG 4
#define WL_STRIDE 33
__global__ __launch_bounds__(512, 2) void decoder_kernel(
    const float* __restrict__ Wih,   // [1024,1]
    const float* __restrict__ Whh,   // [1024,256]
    const float* __restrict__ bb,    // [1024]
    const float* __restrict__ outW,  // [1,256]
    const float* __restrict__ outb,  // [1]
    const float* __restrict__ h0,    // [B,256]
    const float* __restrict__ c0,    // [B,256]
    float* __restrict__ out)         // [B,T,1]
{
    const int bg = blockIdx.x;
    const int t  = threadIdx.x;
    const int lo = t & 255;
    const int hf = t >> 8;           // 0: rows (i,g)   1: rows (f,o)
    const int wv = t >> 6, lane = t & 63;

    const int rowA = hf * 256 + lo;          // i / f
    const int rowB = 512 + hf * 256 + lo;    // g / o

    __shared__ unsigned wl[1024 * WL_STRIDE];   // 135168 B: pairs 96..127 per row
    __shared__ ushort  hU[DG][H_DEC];           // 2 KB
    __shared__ float   exch[DG][2][H_DEC];      // 8 KB
    __shared__ float   red[DG][4];
    __shared__ float   yl[DG];

    // --- stage k-high weights (k 192..255) into LDS as f16 pairs ---
    for (int idx = t; idx < 1024 * 32; idx += 512) {
        int row = idx >> 5, m = idx & 31;
        float2 wv2 = *reinterpret_cast<const float2*>(Whh + (size_t)row * H_DEC + 192 + 2 * m);
        wl[row * WL_STRIDE + m] = as_u32(pack2(wv2.x, wv2.y));
    }

    // --- reg-resident k-low weights (k 0..191): 96 pairs per row ---
    h2f wA[96], wB[96];
    #pragma unroll
    for (int j = 0; j < 96; ++j) {
        float2 a = *reinterpret_cast<const float2*>(Whh + (size_t)rowA * H_DEC + 2 * j);
        float2 b = *reinterpret_cast<const float2*>(Whh + (size_t)rowB * H_DEC + 2 * j);
        wA[j] = pack2(a.x, a.y);
        wB[j] = pack2(b.x, b.y);
    }
    const float wihA = Wih[rowA], wihB = Wih[rowB];
    const float biasA = bb[rowA], biasB = bb[rowB];
    const float ow = outW[lo];
    const float ob = outb[0];

    float c[DG];
    if (!hf) {
        #pragma unroll
        for (int g = 0; g < DG; ++g) {
            int b = bg * DG + g;
            c[g] = c0[(size_t)b * H_DEC + lo];
            *reinterpret_cast<_Float16*>(&hU[g][lo]) = (_Float16)h0[(size_t)b * H_DEC + lo];
        }
    }
    if (t < DG) yl[t] = 0.f;
    __syncthreads();

    for (int s = 0; s < T_DEC; ++s) {
        float accA[DG], accB[DG];
        #pragma unroll
        for (int g = 0; g < DG; ++g) {
            float y = yl[g];
            accA[g] = biasA + wihA * y;
            accB[g] = biasB + wihB * y;
        }

        // k-pairs 0..95 from registers
        #pragma unroll
        for (int m = 0; m < 24; ++m) {
            #pragma unroll
            for (int g = 0; g < DG; ++g) {
                uint4 hv = *reinterpret_cast<const uint4*>(&hU[g][8 * m]);
                accA[g] = FDOT2(wA[4 * m + 0], as_h2(hv.x), accA[g]);
                accB[g] = FDOT2(wB[4 * m + 0], as_h2(hv.x), accB[g]);
                accA[g] = FDOT2(wA[4 * m + 1], as_h2(hv.y), accA[g]);
                accB[g] = FDOT2(wB[4 * m + 1], as_h2(hv.y), accB[g]);
                accA[g] = FDOT2(wA[4 * m + 2], as_h2(hv.z), accA[g]);
                accB[g] = FDOT2(wB[4 * m + 2], as_h2(hv.z), accB[g]);
                accA[g] = FDOT2(wA[4 * m + 3], as_h2(hv.w), accA[g]);
                accB[g] = FDOT2(wB[4 * m + 3], as_h2(hv.w), accB[g]);
            }
        }
        // k-pairs 96..127 from LDS (pad-33, conflict-free)
        #pragma unroll
        for (int m = 24; m < 32; ++m) {
            const int p0 = 4 * m - 96;
            unsigned a0 = wl[rowA * WL_STRIDE + p0 + 0];
            unsigned a1 = wl[rowA * WL_STRIDE + p0 + 1];
            unsigned a2 = wl[rowA * WL_STRIDE + p0 + 2];
            unsigned a3 = wl[rowA * WL_STRIDE + p0 + 3];
            unsigned b0 = wl[rowB * WL_STRIDE + p0 + 0];
            unsigned b1 = wl[rowB * WL_STRIDE + p0 + 1];
            unsigned b2 = wl[rowB * WL_STRIDE + p0 + 2];
            unsigned b3 = wl[rowB * WL_STRIDE + p0 + 3];
            #pragma unroll
            for (int g = 0; g < DG; ++g) {
                uint4 hv = *reinterpret_cast<const uint4*>(&hU[g][8 * m]);
                accA[g] = FDOT2(as_h2(a0), as_h2(hv.x), accA[g]);
                accB[g] = FDOT2(as_h2(b0), as_h2(hv.x), accB[g]);
                accA[g] = FDOT2(as_h2(a1), as_h2(hv.y), accA[g]);
                accB[g] = FDOT2(as_h2(b1), as_h2(hv.y), accB[g]);
                accA[g] = FDOT2(as_h2(a2), as_h2(hv.z), accA[g]);
                accB[g] = FDOT2(as_h2(b2), as_h2(hv.z), accB[g]);
                accA[g] = FDOT2(as_h2(a3), as_h2(hv.w), accA[g]);
                accB[g] = FDOT2(as_h2(b3), as_h2(hv.w), accB[g]);
            }
        }

        if (hf) {
            #pragma unroll
            for (int g = 0; g < DG; ++g) {
                exch[g][0][lo] = accA[g];   // f raw
                exch[g][1][lo] = accB[g];   // o raw
            }
        }
        __syncthreads();   // dots done, exch visible

        if (!hf) {
            #pragma unroll
            for (int g = 0; g < DG; ++g) {
                float fi = sigmoidf_(exch[g][0][lo]);
                float oo = sigmoidf_(exch[g][1][lo]);
                float ii = sigmoidf_(accA[g]);
                float gg = tanhf_(accB[g]);
                c[g] = fi * c[g] + ii * gg;
                float h = oo * tanhf_(c[g]);
                *reinterpret_cast<_Float16*>(&hU[g][lo]) = (_Float16)h;
                float p = h * ow;
                #pragma unroll
                for (int off = 32; off; off >>= 1) p += __shfl_down(p, off);
                if (lane == 0) red[g][wv] = p;
            }
        }
        __syncthreads();   // h + partials visible

        if (t < DG) {
            float y = red[t][0] + red[t][1] + red[t][2] + red[t][3] + ob;
            yl[t] = y;
            out[(size_t)(bg * DG + t) * T_DEC + s] = y;
        }
        __syncthreads();   // y visible
    }
}

extern "C" void kernel_launch(void* const* d_in, const int* in_sizes, int n_in,
                              void* d_out, int out_size, void* d_ws, size_t ws_size,
                              hipStream_t stream) {
    const float* source = (const float*)d_in[0];
    const float* eWih_f = (const float*)d_in[2];
    const float* eWhh_f = (const float*)d_in[3];
    const float* eb_f   = (const float*)d_in[4];
    const float* eWih_b = (const float*)d_in[5];
    const float* eWhh_b = (const float*)d_in[6];
    const float* eb_b   = (const float*)d_in[7];
    const float* dWih   = (const float*)d_in[8];
    const float* dWhh   = (const float*)d_in[9];
    const float* db     = (const float*)d_in[10];
    const float* oW     = (const float*)d_in[11];
    const float* obp    = (const float*)d_in[12];
    float* out = (float*)d_out;

    float* h0 = (float*)d_ws;                  // [1024, 256]
    float* c0 = h0 + (size_t)B_TOT * H_DEC;    // [1024, 256]

    encoder_kernel<<<(B_TOT / EG) * 2, 256, 0, stream>>>(
        source, eWih_f, eWhh_f, eb_f, eWih_b, eWhh_b, eb_b, h0, c0);
    decoder_kernel<<<B_TOT / DG, 512, 0, stream>>>(
        dWih, dWhh, db, oW, obp, h0, c0, out);
}

// Round 3
// 1562.038 us; speedup vs baseline: 6.1357x; 1.6736x over previous
//
#include <hip/hip_runtime.h>
#include <math.h>

#define H_ENC 128
#define H_DEC 256
#define L_SRC 512
#define T_DEC 96
#define B_TOT 1024

typedef _Float16 h2f __attribute__((ext_vector_type(2)));
typedef _Float16 half8 __attribute__((ext_vector_type(8)));
typedef float f32x4 __attribute__((ext_vector_type(4)));

#define MFMA16(A, B, C) __builtin_amdgcn_mfma_f32_16x16x32_f16((A), (B), (C), 0, 0, 0)

#if defined(__has_builtin)
#if __has_builtin(__builtin_amdgcn_fdot2)
#define FDOT2(a, b, c) __builtin_amdgcn_fdot2((a), (b), (c), false)
#endif
#endif
#ifndef FDOT2
#define FDOT2(a, b, c) ((c) + (float)(a).x * (float)(b).x + (float)(a).y * (float)(b).y)
#endif

__device__ __forceinline__ h2f as_h2(unsigned u) { union { unsigned u; h2f h; } x; x.u = u; return x.h; }
__device__ __forceinline__ unsigned as_u32(h2f h) { union { h2f h; unsigned u; } x; x.h = h; return x.u; }
__device__ __forceinline__ h2f pack2(float a, float b) { h2f p; p.x = (_Float16)a; p.y = (_Float16)b; return p; }

__device__ __forceinline__ float sigmoidf_(float x) {
    x = fminf(fmaxf(x, -30.f), 30.f);
    return 1.f / (1.f + __expf(-x));
}
__device__ __forceinline__ float tanhf_(float x) {
    x = fminf(fmaxf(x, -15.f), 15.f);
    float e = __expf(2.f * x);
    return (e - 1.f) / (e + 1.f);
}

// ---------------- Encoder (MFMA) ----------------
// EB=16 batches/block, grid = 64*2 = 128 blocks, 512 threads (8 waves).
// Wave w owns N-tiles {w, 8+w, 16+w, 24+w} = gates i,f,g,o for elems
// [16w,16w+16) -> C-fragments are lane-local for the c/h update.
// Weights: 16 B-frags (f16) in 64 VGPRs. h: f16 in LDS, double-buffered.
#define EB 16
#define HPAD 136   // h row stride in f16 elems (272 B, 16B-aligned, bank-spread)
__global__ __launch_bounds__(512) __attribute__((amdgpu_waves_per_eu(2, 2)))
void encoder_mfma(
    const float* __restrict__ source,
    const float* __restrict__ Wih_f, const float* __restrict__ Whh_f, const float* __restrict__ b_f,
    const float* __restrict__ Wih_b, const float* __restrict__ Whh_b, const float* __restrict__ b_b,
    float* __restrict__ h0, float* __restrict__ c0)
{
    const int dir = blockIdx.x & 1;
    const int bg  = blockIdx.x >> 1;       // 0..63
    const int t   = threadIdx.x;
    const int w   = t >> 6;                // wave 0..7
    const int l   = t & 63;
    const int col = l & 15;
    const int grp = l >> 4;                // 0..3

    const float* Wih = dir ? Wih_b : Wih_f;
    const float* Whh = dir ? Whh_b : Whh_f;
    const float* bb  = dir ? b_b   : b_f;

    __shared__ float    xsT[L_SRC][EB];        // [step][batch] 32 KB
    __shared__ _Float16 hbuf[2][EB][HPAD];     // 8.7 KB, double-buffered

    // stage source transposed: xsT[step][b]
    {
        const float* srcb = source + (size_t)bg * EB * L_SRC;
        for (int i = t; i < EB * L_SRC; i += 512) {
            int step = i >> 4, b = i & 15;
            xsT[step][b] = srcb[(size_t)b * L_SRC + step];
        }
    }

    const int e = 16 * w + col;            // my h-elem 0..127

    // B-frags: frag(t,kt): lane holds Whh[128*t + e][32*kt + 8*grp .. +8] as f16
    half8 wfrag[16];
    #pragma unroll
    for (int tt = 0; tt < 4; ++tt) {
        const float* wr = Whh + (size_t)(128 * tt + e) * H_ENC;
        #pragma unroll
        for (int kt = 0; kt < 4; ++kt) {
            const float* p = wr + 32 * kt + 8 * grp;
            float4 v0 = *reinterpret_cast<const float4*>(p);
            float4 v1 = *reinterpret_cast<const float4*>(p + 4);
            half8 h;
            h[0] = (_Float16)v0.x; h[1] = (_Float16)v0.y; h[2] = (_Float16)v0.z; h[3] = (_Float16)v0.w;
            h[4] = (_Float16)v1.x; h[5] = (_Float16)v1.y; h[6] = (_Float16)v1.z; h[7] = (_Float16)v1.w;
            wfrag[4 * tt + kt] = h;
        }
    }
    float bias4[4], wih4[4];
    #pragma unroll
    for (int tt = 0; tt < 4; ++tt) { bias4[tt] = bb[128 * tt + e]; wih4[tt] = Wih[128 * tt + e]; }

    float c4[4] = {0.f, 0.f, 0.f, 0.f};
    float hout[4] = {0.f, 0.f, 0.f, 0.f};

    for (int i = t; i < EB * HPAD; i += 512) ((_Float16*)hbuf[0])[i] = (_Float16)0.f;
    __syncthreads();

    int cur = 0;
    for (int s = 0; s < L_SRC; ++s) {
        const int step = dir ? (L_SRC - 1 - s) : s;

        // A-frags: lane reads h[cur][batch=col][32*kt + 8*grp .. +8]
        half8 a0 = *reinterpret_cast<const half8*>(&hbuf[cur][col][ 0 + 8 * grp]);
        half8 a1 = *reinterpret_cast<const half8*>(&hbuf[cur][col][32 + 8 * grp]);
        half8 a2 = *reinterpret_cast<const half8*>(&hbuf[cur][col][64 + 8 * grp]);
        half8 a3 = *reinterpret_cast<const half8*>(&hbuf[cur][col][96 + 8 * grp]);

        f32x4 acc0 = {0.f, 0.f, 0.f, 0.f};
        f32x4 acc1 = {0.f, 0.f, 0.f, 0.f};
        f32x4 acc2 = {0.f, 0.f, 0.f, 0.f};
        f32x4 acc3 = {0.f, 0.f, 0.f, 0.f};
        acc0 = MFMA16(a0, wfrag[0],  acc0); acc0 = MFMA16(a1, wfrag[1],  acc0);
        acc0 = MFMA16(a2, wfrag[2],  acc0); acc0 = MFMA16(a3, wfrag[3],  acc0);
        acc1 = MFMA16(a0, wfrag[4],  acc1); acc1 = MFMA16(a1, wfrag[5],  acc1);
        acc1 = MFMA16(a2, wfrag[6],  acc1); acc1 = MFMA16(a3, wfrag[7],  acc1);
        acc2 = MFMA16(a0, wfrag[8],  acc2); acc2 = MFMA16(a1, wfrag[9],  acc2);
        acc2 = MFMA16(a2, wfrag[10], acc2); acc2 = MFMA16(a3, wfrag[11], acc2);
        acc3 = MFMA16(a0, wfrag[12], acc3); acc3 = MFMA16(a1, wfrag[13], acc3);
        acc3 = MFMA16(a2, wfrag[14], acc3); acc3 = MFMA16(a3, wfrag[15], acc3);

        float4 xv = *reinterpret_cast<const float4*>(&xsT[step][4 * grp]);

        #pragma unroll
        for (int r = 0; r < 4; ++r) {
            float x = (r == 0) ? xv.x : (r == 1) ? xv.y : (r == 2) ? xv.z : xv.w;
            float gi = sigmoidf_(acc0[r] + bias4[0] + wih4[0] * x);
            float gf = sigmoidf_(acc1[r] + bias4[1] + wih4[1] * x);
            float gg = tanhf_  (acc2[r] + bias4[2] + wih4[2] * x);
            float go = sigmoidf_(acc3[r] + bias4[3] + wih4[3] * x);
            c4[r] = gf * c4[r] + gi * gg;
            float h = go * tanhf_(c4[r]);
            hout[r] = h;
            hbuf[cur ^ 1][4 * grp + r][e] = (_Float16)h;
        }
        __syncthreads();
        cur ^= 1;
    }

    #pragma unroll
    for (int r = 0; r < 4; ++r) {
        size_t b = (size_t)bg * EB + 4 * grp + r;
        h0[b * (2 * H_ENC) + dir * H_ENC + e] = hout[r];
        c0[b * (2 * H_ENC) + dir * H_ENC + e] = c4[r];
    }
}

// ---------------- Decoder (fdot2, spill-fixed) ----------------
// 512 threads, DG=4 batches, grid = 256 blocks (1/CU).
// Thread owns rows rowA=hf*256+lo (i|f), rowB=512+hf*256+lo (g|o).
// k-pairs 0..95 in 192 VGPRs; pairs 96..127 in 132KB LDS (pad-33).
// waves_per_eu(2,2): force the allocator to the 256-VGPR budget.
#define DG 4
#define WL_STRIDE 33
__global__ __launch_bounds__(512) __attribute__((amdgpu_waves_per_eu(2, 2)))
void decoder_kernel(
    const float* __restrict__ Wih,   // [1024,1]
    const float* __restrict__ Whh,   // [1024,256]
    const float* __restrict__ bb,    // [1024]
    const float* __restrict__ outW,  // [1,256]
    const float* __restrict__ outb,  // [1]
    const float* __restrict__ h0,    // [B,256]
    const float* __restrict__ c0,    // [B,256]
    float* __restrict__ out)         // [B,T,1]
{
    const int bg = blockIdx.x;
    const int t  = threadIdx.x;
    const int lo = t & 255;
    const int hf = t >> 8;           // 0: rows (i,g)   1: rows (f,o)
    const int wv = t >> 6, lane = t & 63;

    const int rowA = hf * 256 + lo;          // i / f
    const int rowB = 512 + hf * 256 + lo;    // g / o

    __shared__ unsigned wl[1024 * WL_STRIDE];   // 135168 B
    __shared__ ushort  hU[DG][H_DEC];
    __shared__ float   exch[DG][2][H_DEC];
    __shared__ float   red[DG][4];
    __shared__ float   yl[DG];

    // k-high weights (k 192..255) -> LDS f16 pairs
    for (int idx = t; idx < 1024 * 32; idx += 512) {
        int row = idx >> 5, m = idx & 31;
        float2 wv2 = *reinterpret_cast<const float2*>(Whh + (size_t)row * H_DEC + 192 + 2 * m);
        wl[row * WL_STRIDE + m] = as_u32(pack2(wv2.x, wv2.y));
    }

    // reg-resident k-low weights (k 0..191): 24 fully-unrolled float4 iters
    h2f wA[96], wB[96];
    #pragma unroll
    for (int jj = 0; jj < 24; ++jj) {
        float4 a0 = *reinterpret_cast<const float4*>(Whh + (size_t)rowA * H_DEC + 8 * jj);
        float4 a1 = *reinterpret_cast<const float4*>(Whh + (size_t)rowA * H_DEC + 8 * jj + 4);
        float4 b0 = *reinterpret_cast<const float4*>(Whh + (size_t)rowB * H_DEC + 8 * jj);
        float4 b1 = *reinterpret_cast<const float4*>(Whh + (size_t)rowB * H_DEC + 8 * jj + 4);
        wA[4 * jj + 0] = pack2(a0.x, a0.y); wA[4 * jj + 1] = pack2(a0.z, a0.w);
        wA[4 * jj + 2] = pack2(a1.x, a1.y); wA[4 * jj + 3] = pack2(a1.z, a1.w);
        wB[4 * jj + 0] = pack2(b0.x, b0.y); wB[4 * jj + 1] = pack2(b0.z, b0.w);
        wB[4 * jj + 2] = pack2(b1.x, b1.y); wB[4 * jj + 3] = pack2(b1.z, b1.w);
    }
    const float wihA = Wih[rowA], wihB = Wih[rowB];
    const float biasA = bb[rowA], biasB = bb[rowB];
    const float ow = outW[lo];
    const float ob = outb[0];

    float c[DG];
    if (!hf) {
        #pragma unroll
        for (int g = 0; g < DG; ++g) {
            int b = bg * DG + g;
            c[g] = c0[(size_t)b * H_DEC + lo];
            *reinterpret_cast<_Float16*>(&hU[g][lo]) = (_Float16)h0[(size_t)b * H_DEC + lo];
        }
    }
    if (t < DG) yl[t] = 0.f;
    __syncthreads();

    for (int s = 0; s < T_DEC; ++s) {
        float accA[DG], accB[DG];
        #pragma unroll
        for (int g = 0; g < DG; ++g) {
            float y = yl[g];
            accA[g] = biasA + wihA * y;
            accB[g] = biasB + wihB * y;
        }

        #pragma unroll
        for (int m = 0; m < 24; ++m) {
            #pragma unroll
            for (int g = 0; g < DG; ++g) {
                uint4 hv = *reinterpret_cast<const uint4*>(&hU[g][8 * m]);
                accA[g] = FDOT2(wA[4 * m + 0], as_h2(hv.x), accA[g]);
                accB[g] = FDOT2(wB[4 * m + 0], as_h2(hv.x), accB[g]);
                accA[g] = FDOT2(wA[4 * m + 1], as_h2(hv.y), accA[g]);
                accB[g] = FDOT2(wB[4 * m + 1], as_h2(hv.y), accB[g]);
                accA[g] = FDOT2(wA[4 * m + 2], as_h2(hv.z), accA[g]);
                accB[g] = FDOT2(wB[4 * m + 2], as_h2(hv.z), accB[g]);
                accA[g] = FDOT2(wA[4 * m + 3], as_h2(hv.w), accA[g]);
                accB[g] = FDOT2(wB[4 * m + 3], as_h2(hv.w), accB[g]);
            }
        }
        #pragma unroll
        for (int m = 24; m < 32; ++m) {
            const int p0 = 4 * m - 96;
            unsigned a0 = wl[rowA * WL_STRIDE + p0 + 0];
            unsigned a1 = wl[rowA * WL_STRIDE + p0 + 1];
            unsigned a2 = wl[rowA * WL_STRIDE + p0 + 2];
            unsigned a3 = wl[rowA * WL_STRIDE + p0 + 3];
            unsigned b0 = wl[rowB * WL_STRIDE + p0 + 0];
            unsigned b1 = wl[rowB * WL_STRIDE + p0 + 1];
            unsigned b2 = wl[rowB * WL_STRIDE + p0 + 2];
            unsigned b3 = wl[rowB * WL_STRIDE + p0 + 3];
            #pragma unroll
            for (int g = 0; g < DG; ++g) {
                uint4 hv = *reinterpret_cast<const uint4*>(&hU[g][8 * m]);
                accA[g] = FDOT2(as_h2(a0), as_h2(hv.x), accA[g]);
                accB[g] = FDOT2(as_h2(b0), as_h2(hv.x), accB[g]);
                accA[g] = FDOT2(as_h2(a1), as_h2(hv.y), accA[g]);
                accB[g] = FDOT2(as_h2(b1), as_h2(hv.y), accB[g]);
                accA[g] = FDOT2(as_h2(a2), as_h2(hv.z), accA[g]);
                accB[g] = FDOT2(as_h2(b2), as_h2(hv.z), accB[g]);
                accA[g] = FDOT2(as_h2(a3), as_h2(hv.w), accA[g]);
                accB[g] = FDOT2(as_h2(b3), as_h2(hv.w), accB[g]);
            }
        }

        if (hf) {
            #pragma unroll
            for (int g = 0; g < DG; ++g) {
                exch[g][0][lo] = accA[g];   // f raw
                exch[g][1][lo] = accB[g];   // o raw
            }
        }
        __syncthreads();

        if (!hf) {
            #pragma unroll
            for (int g = 0; g < DG; ++g) {
                float fi = sigmoidf_(exch[g][0][lo]);
                float oo = sigmoidf_(exch[g][1][lo]);
                float ii = sigmoidf_(accA[g]);
                float gg = tanhf_(accB[g]);
                c[g] = fi * c[g] + ii * gg;
                float h = oo * tanhf_(c[g]);
                *reinterpret_cast<_Float16*>(&hU[g][lo]) = (_Float16)h;
                float p = h * ow;
                #pragma unroll
                for (int off = 32; off; off >>= 1) p += __shfl_down(p, off);
                if (lane == 0) red[g][wv] = p;
            }
        }
        __syncthreads();

        if (t < DG) {
            float y = red[t][0] + red[t][1] + red[t][2] + red[t][3] + ob;
            yl[t] = y;
            out[(size_t)(bg * DG + t) * T_DEC + s] = y;
        }
        __syncthreads();
    }
}

extern "C" void kernel_launch(void* const* d_in, const int* in_sizes, int n_in,
                              void* d_out, int out_size, void* d_ws, size_t ws_size,
                              hipStream_t stream) {
    const float* source = (const float*)d_in[0];
    const float* eWih_f = (const float*)d_in[2];
    const float* eWhh_f = (const float*)d_in[3];
    const float* eb_f   = (const float*)d_in[4];
    const float* eWih_b = (const float*)d_in[5];
    const float* eWhh_b = (const float*)d_in[6];
    const float* eb_b   = (const float*)d_in[7];
    const float* dWih   = (const float*)d_in[8];
    const float* dWhh   = (const float*)d_in[9];
    const float* db     = (const float*)d_in[10];
    const float* oW     = (const float*)d_in[11];
    const float* obp    = (const float*)d_in[12];
    float* out = (float*)d_out;

    float* h0 = (float*)d_ws;                  // [1024, 256]
    float* c0 = h0 + (size_t)B_TOT * H_DEC;    // [1024, 256]

    encoder_mfma<<<64 * 2, 512, 0, stream>>>(
        source, eWih_f, eWhh_f, eb_f, eWih_b, eWhh_b, eb_b, h0, c0);
    decoder_kernel<<<B_TOT / DG, 512, 0, stream>>>(
        dWih, dWhh, db, oW, obp, h0, c0, out);
}

// Round 4
// 1146.398 us; speedup vs baseline: 8.3603x; 1.3626x over previous
//
#include <hip/hip_runtime.h>
#include <math.h>

#define H_ENC 128
#define H_DEC 256
#define L_SRC 512
#define T_DEC 96
#define B_TOT 1024

typedef _Float16 h2f __attribute__((ext_vector_type(2)));
typedef _Float16 half8 __attribute__((ext_vector_type(8)));
typedef float f32x4 __attribute__((ext_vector_type(4)));
typedef unsigned u32x32 __attribute__((ext_vector_type(32)));

#define MFMA16(A, B, C) __builtin_amdgcn_mfma_f32_16x16x32_f16((A), (B), (C), 0, 0, 0)

#if defined(__has_builtin)
#if __has_builtin(__builtin_amdgcn_fdot2)
#define FDOT2(a, b, c) __builtin_amdgcn_fdot2((a), (b), (c), false)
#endif
#endif
#ifndef FDOT2
#define FDOT2(a, b, c) ((c) + (float)(a).x * (float)(b).x + (float)(a).y * (float)(b).y)
#endif

__device__ __forceinline__ h2f as_h2(unsigned u) { union { unsigned u; h2f h; } x; x.u = u; return x.h; }
__device__ __forceinline__ unsigned as_u32(h2f h) { union { h2f h; unsigned u; } x; x.h = h; return x.u; }
__device__ __forceinline__ h2f pack2(float a, float b) { h2f p; p.x = (_Float16)a; p.y = (_Float16)b; return p; }

// clamp-free, division-free: v_exp + v_rcp only (NaN-safe: exp->inf/0 gives 0/1 limits)
__device__ __forceinline__ float sigmoidf_(float x) {
    return __builtin_amdgcn_rcpf(1.f + __expf(-x));
}
__device__ __forceinline__ float tanhf_(float x) {
    return 1.f - 2.f * __builtin_amdgcn_rcpf(__expf(2.f * x) + 1.f);
}

// ---------------- Encoder (MFMA) ----------------
// EB=16 batches/block, grid = 64*2 = 128 blocks, 512 threads (8 waves).
// Wave w owns N-tiles {w, 8+w, 16+w, 24+w} = gates i,f,g,o for elems
// [16w,16w+16) -> C-fragments are lane-local for the c/h update.
#define EB 16
#define HPAD 136
__global__ __launch_bounds__(512, 2)
void encoder_mfma(
    const float* __restrict__ source,
    const float* __restrict__ Wih_f, const float* __restrict__ Whh_f, const float* __restrict__ b_f,
    const float* __restrict__ Wih_b, const float* __restrict__ Whh_b, const float* __restrict__ b_b,
    float* __restrict__ h0, float* __restrict__ c0)
{
    const int dir = blockIdx.x & 1;
    const int bg  = blockIdx.x >> 1;
    const int t   = threadIdx.x;
    const int w   = t >> 6;
    const int l   = t & 63;
    const int col = l & 15;
    const int grp = l >> 4;

    const float* Wih = dir ? Wih_b : Wih_f;
    const float* Whh = dir ? Whh_b : Whh_f;
    const float* bb  = dir ? b_b   : b_f;

    __shared__ float    xsT[L_SRC][EB];
    __shared__ _Float16 hbuf[2][EB][HPAD];

    {
        const float* srcb = source + (size_t)bg * EB * L_SRC;
        for (int i = t; i < EB * L_SRC; i += 512) {
            int step = i >> 4, b = i & 15;
            xsT[step][b] = srcb[(size_t)b * L_SRC + step];
        }
    }

    const int e = 16 * w + col;

    half8 wfrag[16];
    #pragma unroll
    for (int tt = 0; tt < 4; ++tt) {
        const float* wr = Whh + (size_t)(128 * tt + e) * H_ENC;
        #pragma unroll
        for (int kt = 0; kt < 4; ++kt) {
            const float* p = wr + 32 * kt + 8 * grp;
            float4 v0 = *reinterpret_cast<const float4*>(p);
            float4 v1 = *reinterpret_cast<const float4*>(p + 4);
            half8 h;
            h[0] = (_Float16)v0.x; h[1] = (_Float16)v0.y; h[2] = (_Float16)v0.z; h[3] = (_Float16)v0.w;
            h[4] = (_Float16)v1.x; h[5] = (_Float16)v1.y; h[6] = (_Float16)v1.z; h[7] = (_Float16)v1.w;
            wfrag[4 * tt + kt] = h;
        }
    }
    float bias4[4], wih4[4];
    #pragma unroll
    for (int tt = 0; tt < 4; ++tt) { bias4[tt] = bb[128 * tt + e]; wih4[tt] = Wih[128 * tt + e]; }

    float c4[4] = {0.f, 0.f, 0.f, 0.f};
    float hout[4] = {0.f, 0.f, 0.f, 0.f};

    for (int i = t; i < EB * HPAD; i += 512) ((_Float16*)hbuf[0])[i] = (_Float16)0.f;
    __syncthreads();

    int cur = 0;
    for (int s = 0; s < L_SRC; ++s) {
        const int step = dir ? (L_SRC - 1 - s) : s;

        // x first (independent of h) so its latency hides under MFMA
        float4 xv = *reinterpret_cast<const float4*>(&xsT[step][4 * grp]);

        half8 a0 = *reinterpret_cast<const half8*>(&hbuf[cur][col][ 0 + 8 * grp]);
        half8 a1 = *reinterpret_cast<const half8*>(&hbuf[cur][col][32 + 8 * grp]);
        half8 a2 = *reinterpret_cast<const half8*>(&hbuf[cur][col][64 + 8 * grp]);
        half8 a3 = *reinterpret_cast<const half8*>(&hbuf[cur][col][96 + 8 * grp]);

        f32x4 acc0 = {0.f, 0.f, 0.f, 0.f};
        f32x4 acc1 = {0.f, 0.f, 0.f, 0.f};
        f32x4 acc2 = {0.f, 0.f, 0.f, 0.f};
        f32x4 acc3 = {0.f, 0.f, 0.f, 0.f};
        acc0 = MFMA16(a0, wfrag[0],  acc0); acc0 = MFMA16(a1, wfrag[1],  acc0);
        acc0 = MFMA16(a2, wfrag[2],  acc0); acc0 = MFMA16(a3, wfrag[3],  acc0);
        acc1 = MFMA16(a0, wfrag[4],  acc1); acc1 = MFMA16(a1, wfrag[5],  acc1);
        acc1 = MFMA16(a2, wfrag[6],  acc1); acc1 = MFMA16(a3, wfrag[7],  acc1);
        acc2 = MFMA16(a0, wfrag[8],  acc2); acc2 = MFMA16(a1, wfrag[9],  acc2);
        acc2 = MFMA16(a2, wfrag[10], acc2); acc2 = MFMA16(a3, wfrag[11], acc2);
        acc3 = MFMA16(a0, wfrag[12], acc3); acc3 = MFMA16(a1, wfrag[13], acc3);
        acc3 = MFMA16(a2, wfrag[14], acc3); acc3 = MFMA16(a3, wfrag[15], acc3);

        #pragma unroll
        for (int r = 0; r < 4; ++r) {
            float x = (r == 0) ? xv.x : (r == 1) ? xv.y : (r == 2) ? xv.z : xv.w;
            float gi = sigmoidf_(acc0[r] + bias4[0] + wih4[0] * x);
            float gf = sigmoidf_(acc1[r] + bias4[1] + wih4[1] * x);
            float gg = tanhf_  (acc2[r] + bias4[2] + wih4[2] * x);
            float go = sigmoidf_(acc3[r] + bias4[3] + wih4[3] * x);
            c4[r] = gf * c4[r] + gi * gg;
            float h = go * tanhf_(c4[r]);
            hout[r] = h;
            hbuf[cur ^ 1][4 * grp + r][e] = (_Float16)h;
        }
        __syncthreads();
        cur ^= 1;
    }

    #pragma unroll
    for (int r = 0; r < 4; ++r) {
        size_t b = (size_t)bg * EB + 4 * grp + r;
        h0[b * (2 * H_ENC) + dir * H_ENC + e] = hout[r];
        c0[b * (2 * H_ENC) + dir * H_ENC + e] = c4[r];
    }
}

// ---------------- Decoder (fdot2, SSA-vector weights) ----------------
// 512 threads, DG=4 batches, grid = 256 blocks (1/CU, 256-VGPR budget via
// __launch_bounds__(512,2)). Weights for k<192 in six u32x32 SSA vectors
// (96+96 VGPRs, constant-index only -> cannot be demoted to scratch as an
// array); k 192..255 in 132KB LDS (pad-33).
#define DG 4
#define WL_STRIDE 33

#define SETWA(p, v) do { if ((p) < 32) WA0[(p)&31] = (v); else if ((p) < 64) WA1[(p)&31] = (v); else WA2[(p)&31] = (v); } while (0)
#define SETWB(p, v) do { if ((p) < 32) WB0[(p)&31] = (v); else if ((p) < 64) WB1[(p)&31] = (v); else WB2[(p)&31] = (v); } while (0)
#define GETWA(p) ((p) < 32 ? WA0[(p)&31] : ((p) < 64 ? WA1[(p)&31] : WA2[(p)&31]))
#define GETWB(p) ((p) < 32 ? WB0[(p)&31] : ((p) < 64 ? WB1[(p)&31] : WB2[(p)&31]))

__global__ __launch_bounds__(512, 2)
void decoder_kernel(
    const float* __restrict__ Wih,   // [1024,1]
    const float* __restrict__ Whh,   // [1024,256]
    const float* __restrict__ bb,    // [1024]
    const float* __restrict__ outW,  // [1,256]
    const float* __restrict__ outb,  // [1]
    const float* __restrict__ h0,    // [B,256]
    const float* __restrict__ c0,    // [B,256]
    float* __restrict__ out)         // [B,T,1]
{
    const int bg = blockIdx.x;
    const int t  = threadIdx.x;
    const int lo = t & 255;
    const int hf = t >> 8;           // 0: rows (i,g)   1: rows (f,o)
    const int wv = t >> 6, lane = t & 63;

    const int rowA = hf * 256 + lo;          // i / f
    const int rowB = 512 + hf * 256 + lo;    // g / o

    __shared__ unsigned wl[1024 * WL_STRIDE];   // 135168 B
    __shared__ ushort  hU[DG][H_DEC];
    __shared__ float   exch[DG][2][H_DEC];
    __shared__ float   red[DG][4];
    __shared__ float   yl[DG];

    // k-high weights (k 192..255) -> LDS f16 pairs
    for (int idx = t; idx < 1024 * 32; idx += 512) {
        int row = idx >> 5, m = idx & 31;
        float2 wv2 = *reinterpret_cast<const float2*>(Whh + (size_t)row * H_DEC + 192 + 2 * m);
        wl[row * WL_STRIDE + m] = as_u32(pack2(wv2.x, wv2.y));
    }

    // k-low weights (k 0..191) -> six SSA vectors (96 pairs per row-class)
    u32x32 WA0, WA1, WA2, WB0, WB1, WB2;
    #pragma unroll
    for (int jj = 0; jj < 24; ++jj) {
        float4 a0 = *reinterpret_cast<const float4*>(Whh + (size_t)rowA * H_DEC + 8 * jj);
        float4 a1 = *reinterpret_cast<const float4*>(Whh + (size_t)rowA * H_DEC + 8 * jj + 4);
        float4 b0 = *reinterpret_cast<const float4*>(Whh + (size_t)rowB * H_DEC + 8 * jj);
        float4 b1 = *reinterpret_cast<const float4*>(Whh + (size_t)rowB * H_DEC + 8 * jj + 4);
        SETWA(4 * jj + 0, as_u32(pack2(a0.x, a0.y)));
        SETWA(4 * jj + 1, as_u32(pack2(a0.z, a0.w)));
        SETWA(4 * jj + 2, as_u32(pack2(a1.x, a1.y)));
        SETWA(4 * jj + 3, as_u32(pack2(a1.z, a1.w)));
        SETWB(4 * jj + 0, as_u32(pack2(b0.x, b0.y)));
        SETWB(4 * jj + 1, as_u32(pack2(b0.z, b0.w)));
        SETWB(4 * jj + 2, as_u32(pack2(b1.x, b1.y)));
        SETWB(4 * jj + 3, as_u32(pack2(b1.z, b1.w)));
    }
    const float wihA = Wih[rowA], wihB = Wih[rowB];
    const float biasA = bb[rowA], biasB = bb[rowB];
    const float ow = outW[lo];
    const float ob = outb[0];

    float c[DG];
    if (!hf) {
        #pragma unroll
        for (int g = 0; g < DG; ++g) {
            int b = bg * DG + g;
            c[g] = c0[(size_t)b * H_DEC + lo];
            *reinterpret_cast<_Float16*>(&hU[g][lo]) = (_Float16)h0[(size_t)b * H_DEC + lo];
        }
    }
    if (t < DG) yl[t] = 0.f;
    __syncthreads();

    for (int s = 0; s < T_DEC; ++s) {
        float accA[DG], accB[DG];
        #pragma unroll
        for (int g = 0; g < DG; ++g) {
            float y = yl[g];
            accA[g] = biasA + wihA * y;
            accB[g] = biasB + wihB * y;
        }

        #pragma unroll
        for (int m = 0; m < 24; ++m) {
            #pragma unroll
            for (int g = 0; g < DG; ++g) {
                uint4 hv = *reinterpret_cast<const uint4*>(&hU[g][8 * m]);
                accA[g] = FDOT2(as_h2(GETWA(4 * m + 0)), as_h2(hv.x), accA[g]);
                accB[g] = FDOT2(as_h2(GETWB(4 * m + 0)), as_h2(hv.x), accB[g]);
                accA[g] = FDOT2(as_h2(GETWA(4 * m + 1)), as_h2(hv.y), accA[g]);
                accB[g] = FDOT2(as_h2(GETWB(4 * m + 1)), as_h2(hv.y), accB[g]);
                accA[g] = FDOT2(as_h2(GETWA(4 * m + 2)), as_h2(hv.z), accA[g]);
                accB[g] = FDOT2(as_h2(GETWB(4 * m + 2)), as_h2(hv.z), accB[g]);
                accA[g] = FDOT2(as_h2(GETWA(4 * m + 3)), as_h2(hv.w), accA[g]);
                accB[g] = FDOT2(as_h2(GETWB(4 * m + 3)), as_h2(hv.w), accB[g]);
            }
        }
        #pragma unroll
        for (int m = 24; m < 32; ++m) {
            const int p0 = 4 * m - 96;
            unsigned a0 = wl[rowA * WL_STRIDE + p0 + 0];
            unsigned a1 = wl[rowA * WL_STRIDE + p0 + 1];
            unsigned a2 = wl[rowA * WL_STRIDE + p0 + 2];
            unsigned a3 = wl[rowA * WL_STRIDE + p0 + 3];
            unsigned b0 = wl[rowB * WL_STRIDE + p0 + 0];
            unsigned b1 = wl[rowB * WL_STRIDE + p0 + 1];
            unsigned b2 = wl[rowB * WL_STRIDE + p0 + 2];
            unsigned b3 = wl[rowB * WL_STRIDE + p0 + 3];
            #pragma unroll
            for (int g = 0; g < DG; ++g) {
                uint4 hv = *reinterpret_cast<const uint4*>(&hU[g][8 * m]);
                accA[g] = FDOT2(as_h2(a0), as_h2(hv.x), accA[g]);
                accB[g] = FDOT2(as_h2(b0), as_h2(hv.x), accB[g]);
                accA[g] = FDOT2(as_h2(a1), as_h2(hv.y), accA[g]);
                accB[g] = FDOT2(as_h2(b1), as_h2(hv.y), accB[g]);
                accA[g] = FDOT2(as_h2(a2), as_h2(hv.z), accA[g]);
                accB[g] = FDOT2(as_h2(b2), as_h2(hv.z), accB[g]);
                accA[g] = FDOT2(as_h2(a3), as_h2(hv.w), accA[g]);
                accB[g] = FDOT2(as_h2(b3), as_h2(hv.w), accB[g]);
            }
        }

        if (hf) {
            #pragma unroll
            for (int g = 0; g < DG; ++g) {
                exch[g][0][lo] = accA[g];   // f raw
                exch[g][1][lo] = accB[g];   // o raw
            }
        }
        __syncthreads();

        if (!hf) {
            #pragma unroll
            for (int g = 0; g < DG; ++g) {
                float fi = sigmoidf_(exch[g][0][lo]);
                float oo = sigmoidf_(exch[g][1][lo]);
                float ii = sigmoidf_(accA[g]);
                float gg = tanhf_(accB[g]);
                c[g] = fi * c[g] + ii * gg;
                float h = oo * tanhf_(c[g]);
                *reinterpret_cast<_Float16*>(&hU[g][lo]) = (_Float16)h;
                float p = h * ow;
                #pragma unroll
                for (int off = 32; off; off >>= 1) p += __shfl_down(p, off);
                if (lane == 0) red[g][wv] = p;
            }
        }
        __syncthreads();

        if (t < DG) {
            float y = red[t][0] + red[t][1] + red[t][2] + red[t][3] + ob;
            yl[t] = y;
            out[(size_t)(bg * DG + t) * T_DEC + s] = y;
        }
        __syncthreads();
    }
}

extern "C" void kernel_launch(void* const* d_in, const int* in_sizes, int n_in,
                              void* d_out, int out_size, void* d_ws, size_t ws_size,
                              hipStream_t stream) {
    const float* source = (const float*)d_in[0];
    const float* eWih_f = (const float*)d_in[2];
    const float* eWhh_f = (const float*)d_in[3];
    const float* eb_f   = (const float*)d_in[4];
    const float* eWih_b = (const float*)d_in[5];
    const float* eWhh_b = (const float*)d_in[6];
    const float* eb_b   = (const float*)d_in[7];
    const float* dWih   = (const float*)d_in[8];
    const float* dWhh   = (const float*)d_in[9];
    const float* db     = (const float*)d_in[10];
    const float* oW     = (const float*)d_in[11];
    const float* obp    = (const float*)d_in[12];
    float* out = (float*)d_out;

    float* h0 = (float*)d_ws;
    float* c0 = h0 + (size_t)B_TOT * H_DEC;

    encoder_mfma<<<64 * 2, 512, 0, stream>>>(
        source, eWih_f, eWhh_f, eb_f, eWih_b, eWhh_b, eb_b, h0, c0);
    decoder_kernel<<<B_TOT / DG, 512, 0, stream>>>(
        dWih, dWhh, db, oW, obp, h0, c0, out);
}